// Round 10
// baseline (304.494 us; speedup 1.0000x reference)
//
#include <hip/hip_runtime.h>
#include <hip/hip_bf16.h>

#define NN 50000
#define NE 800000
#define DD 128
#define NT 3
#define AGGW 384           // T*D mailbox columns per node
#define EM 64              // rows per k_node GEMM tile
#define EM2 128            // rows per k_msg GEMM tile
#define LDK 136            // padded LDS row (bf16 elems) for k_msg W tile
#define CB 32              // k_node: output cols per W-panel stage
#define LDK2 520           // k_node: padded K-row (512+8)
#define EPB 2048           // edges per scatter block (391 blocks)
#define NTILES_MAX (((NN + EM - 1) / EM) + NT)      // 785 worst-case row tiles
#define NTILE_PAD (((NTILES_MAX + 7) / 8) * 8)      // 792, padded for XCD swizzle

typedef __bf16 bf16x8 __attribute__((ext_vector_type(8)));
typedef float f32x4 __attribute__((ext_vector_type(4)));
typedef unsigned short u16x8 __attribute__((ext_vector_type(8)));
typedef unsigned int u32x4 __attribute__((ext_vector_type(4)));

__device__ __forceinline__ unsigned short f2b(float f) {
    __hip_bfloat16 h = __float2bfloat16(f);
    return __builtin_bit_cast(unsigned short, h);
}
__device__ __forceinline__ float b2f(unsigned int u16bits) {
    unsigned int x = u16bits << 16;
    return __builtin_bit_cast(float, x);
}

// ---------------- K0: pre-convert f32 -> bf16 (nf, We, Wn) + zero rowcnt/cnts ----------------
__global__ void k_prep(const float* __restrict__ nf, const float* __restrict__ We,
                       const float* __restrict__ Wn, unsigned short* __restrict__ nfb,
                       unsigned short* __restrict__ Web, unsigned short* __restrict__ Wnb,
                       int* __restrict__ rowcnt, int* __restrict__ cnts) {
    size_t i = (size_t)blockIdx.x * blockDim.x + threadIdx.x;
    if (i < NN) rowcnt[i] = 0;
    if (i >= NN && i < NN + 16) cnts[i - NN] = 0;
    const size_t n0 = (size_t)NN * DD / 8;
    const size_t n1 = (size_t)NT * DD * DD / 8;
    const size_t n2 = (size_t)NT * DD * 512 / 8;
    size_t total = n0 + n1 + n2;
    for (size_t p = i; p < total; p += (size_t)gridDim.x * blockDim.x) {
        const float* s; unsigned short* d; size_t off;
        if (p < n0)            { s = nf; d = nfb; off = p; }
        else if (p < n0 + n1)  { s = We; d = Web; off = p - n0; }
        else                   { s = Wn; d = Wnb; off = p - n0 - n1; }
        const float4* f4 = (const float4*)(s + off * 8);
        float4 x = f4[0], y = f4[1];
        u16x8 u = { f2b(x.x), f2b(x.y), f2b(x.z), f2b(x.w),
                    f2b(y.x), f2b(y.y), f2b(y.z), f2b(y.w) };
        *(u16x8*)(d + off * 8) = u;
    }
}

// ---------------- K1: per-node degree histogram (direct global atomics) + node-type hist ----
// Replaces the binned LDS histogram: 800k atomicAdd over 50k L2-resident counters
// (lambda=16 hits/counter). Guideline 12/m20: global atomics are device-scope and
// per-wave coalesced on gfx950.
__global__ __launch_bounds__(256) void k_hist(const int* __restrict__ edst,
        const int* __restrict__ ntp, int* __restrict__ rowcnt, int* __restrict__ cnts) {
    __shared__ int ln[3];
    int tid = threadIdx.x;
    if (tid < 3) ln[tid] = 0;
    __syncthreads();
    int i0 = blockIdx.x * 256 + tid;
    int stride = gridDim.x * 256;
    for (int p = i0; p < NE; p += stride) atomicAdd(&rowcnt[edst[p]], 1);
    for (int p = i0; p < NN; p += stride) atomicAdd(&ln[ntp[p]], 1);
    __syncthreads();
    if (tid < 3) atomicAdd(&cnts[6 + tid], ln[tid]);
}

// ---------------- K2: single-block scan of 50k degrees -> rowptr, rowcur ----------------
// 1024 threads x 49 elems: seq-sum pass, wave+block scan of 1024 partials, prefix
// write-back pass (second read is L2-hot). No runtime-indexed local arrays (rule #20).
__global__ __launch_bounds__(1024) void k_scan(const int* __restrict__ rowcnt,
        int* __restrict__ rowptr, int* __restrict__ rowcur) {
    __shared__ int ws[16];
    int tid = threadIdx.x;
    const int PT = 49;                       // 1024*49 = 50176 >= NN
    int i0 = tid * PT;
    int s = 0;
    for (int k = 0; k < PT; ++k) {
        int i = i0 + k;
        if (i < NN) s += rowcnt[i];
    }
    int lane = tid & 63, wv = tid >> 6;      // 16 waves
    int v = s;
    for (int d = 1; d < 64; d <<= 1) {
        int u = __shfl_up(v, d);
        if (lane >= d) v += u;
    }
    if (lane == 63) ws[wv] = v;
    __syncthreads();
    if (wv == 0 && lane < 16) {
        int wsum = ws[lane];
        int w2 = wsum;
        for (int d = 1; d < 16; d <<= 1) {
            int u = __shfl_up(w2, d);
            if (lane >= d) w2 += u;
        }
        ws[lane] = w2 - wsum;                // exclusive wave prefix
    }
    __syncthreads();
    int run = (v - s) + ws[wv];              // exclusive prefix for this thread's chunk
    for (int k = 0; k < PT; ++k) {
        int i = i0 + k;
        if (i < NN) {
            rowptr[i] = run;
            rowcur[i] = run;
            run += rowcnt[i];
        }
    }
    if (tid == 1023) rowptr[NN] = NE;
}

// ---------------- K3: MERGED direct scatter + node-type sort + message GEMM ----------------
// Scatter role is now BARRIER-FREE: pos = atomicAdd(&rowcur[dst],1); pe[pos] = payload.
// No LDS phases (R9 showed the 3-phase binned structure, not atomic contention, was the
// ~40us cost). pe lands node-grouped directly => k_binsort deleted.
// payload: rowid = t*NN+src (18b) | t<<25 (2b)
__global__ __launch_bounds__(512) void k_mid(
        const unsigned short* __restrict__ nfb, const unsigned short* __restrict__ Web,
        const float* __restrict__ be, unsigned short* __restrict__ M,
        const int* __restrict__ esrc, const int* __restrict__ edst,
        const int* __restrict__ et, const int* __restrict__ ntp,
        int* __restrict__ rowcur, int* __restrict__ cnts,
        int* __restrict__ pe, int* __restrict__ sn, int* __restrict__ rnk) {
    const int NEB = (NE + EPB - 1) / EPB;    // 391 edge-scatter blocks
    const int NCH2 = (NN + 511) / 512;       // 98 node-type blocks
    const int TILES = (NN + EM2 - 1) / EM2;  // 391 msg tiles per type
    __shared__ unsigned short Wsm[DD][LDK];  // 34 KB (msg role; tiny alias for role 2)
    int tid = threadIdx.x, b = blockIdx.x;

    if (b < NEB) {                           // ---- role 1: direct scatter (no LDS) ----
        int e0 = b * EPB;
#pragma unroll
        for (int i = 0; i < EPB; i += 512) {
            int e = e0 + i + tid;
            if (e < NE) {
                int d = edst[e];
                int t = et[e];
                int pos = atomicAdd(&rowcur[d], 1);
                pe[pos] = (t * NN + esrc[e]) | (t << 25);
            }
        }
    } else if (b < NEB + NCH2) {             // ---- role 2: node-type sort (512 thr) ----
        int* lcnt = (int*)&Wsm[0][0];
        int* lbase = lcnt + 4;
        if (tid < 3) lcnt[tid] = 0;
        __syncthreads();
        int p = (b - NEB) * 512 + tid;
        int t = -1, rank = 0;
        if (p < NN) { t = ntp[p]; rank = atomicAdd(&lcnt[t], 1); }
        __syncthreads();
        if (tid < 3) lbase[tid] = atomicAdd(&cnts[9 + tid], lcnt[tid]);
        __syncthreads();
        if (p < NN) {
            int c0 = cnts[6], c1 = cnts[7];
            int off = (t == 0) ? 0 : (t == 1) ? c0 : c0 + c1;
            int pos = off + lbase[t] + rank;
            sn[pos] = p;
            rnk[p] = pos;                    // inverse permutation for sorted aggb
        }
    } else {                                 // ---- role 3: message GEMM (512 thr) ----
        int bb = b - NEB - NCH2;
        int t = bb / TILES, tile = bb % TILES;
        int base = tile * EM2;
        int m = min(EM2, NN - base);
        { // stage Web[t] 128x128: 512 thr x 32 cols
            int row = tid >> 2, c0 = (tid & 3) * 32;
            const u16x8* src = (const u16x8*)(Web + ((size_t)t * DD + row) * DD + c0);
#pragma unroll
            for (int v = 0; v < 4; ++v) *(u16x8*)&Wsm[row][c0 + v * 8] = src[v];
        }
        __syncthreads();

        int wave = tid >> 6, l = tid & 63, lr2 = l & 15, kg = l >> 4;
        int arow = min(base + wave * 16 + lr2, NN - 1);
        const u16x8* Arow = (const u16x8*)(nfb + (size_t)arow * DD);
        f32x4 acc[8];
#pragma unroll
        for (int n = 0; n < 8; n++) acc[n] = (f32x4){0.f, 0.f, 0.f, 0.f};
#pragma unroll
        for (int k0 = 0; k0 < DD; k0 += 32) {
            bf16x8 a = __builtin_bit_cast(bf16x8, Arow[(k0 >> 3) + kg]);
#pragma unroll
            for (int n = 0; n < 8; n++) {
                bf16x8 bbv = *(const bf16x8*)&Wsm[n * 16 + lr2][k0 + kg * 8];
                acc[n] = __builtin_amdgcn_mfma_f32_16x16x32_bf16(a, bbv, acc[n], 0, 0, 0);
            }
        }
        unsigned short* Mt = M + (size_t)t * NN * DD;
#pragma unroll
        for (int n = 0; n < 8; n++) {
            int col = n * 16 + lr2;
            float bias = be[t * DD + col];
#pragma unroll
            for (int r = 0; r < 4; r++) {
                int row = wave * 16 + kg * 4 + r;
                if (row < m) {
                    float v = acc[n][r] + bias;
                    Mt[(size_t)(base + row) * DD + col] = f2b(fmaxf(v, 0.f));
                }
            }
        }
    }
}

// ---------------- K5: gather-reduce, one 16-lane group per node ----------------
// CLOSED at its DRAM-random floor (R3/R4/R5: 38-40us, FETCH pinned at 95 MB).
// Output row written at rnk[node] (sn order) so k_node's agg reads are contiguous.
__global__ __launch_bounds__(128) void k_agg(const unsigned short* __restrict__ M,
        const int* __restrict__ rowptr, const int* __restrict__ pe,
        const int* __restrict__ rnk, unsigned short* __restrict__ aggb) {
    int node = blockIdx.x * 8 + (threadIdx.x >> 4);     // NN = 6250*8 exactly
    int q = threadIdx.x & 15;                           // lane within group: cols q*8..q*8+7
    int beg = rowptr[node], end = rowptr[node + 1];
    const u32x4* Mu4 = (const u32x4*)M;                 // one M row = 16 u32x4
    float a0[8] = {0,0,0,0,0,0,0,0};
    float a1[8] = {0,0,0,0,0,0,0,0};
    float a2[8] = {0,0,0,0,0,0,0,0};
    int e = beg;
    while (e < end) {                                   // trip count uniform within group
        unsigned int p[8];
        u32x4 v[8];
#pragma unroll
        for (int j = 0; j < 8; ++j) p[j] = pe[min(e + j, end - 1)];
#pragma unroll
        for (int j = 0; j < 8; ++j)
            if (e + j < end) v[j] = Mu4[(size_t)(p[j] & 0x3FFFFu) * 16 + q];
#pragma unroll
        for (int j = 0; j < 8; ++j) {
            if (e + j < end) {
                int t = p[j] >> 25;
                float f0 = b2f(v[j][0] & 0xFFFF), f1 = b2f(v[j][0] >> 16);
                float f2 = b2f(v[j][1] & 0xFFFF), f3 = b2f(v[j][1] >> 16);
                float f4 = b2f(v[j][2] & 0xFFFF), f5 = b2f(v[j][2] >> 16);
                float f6 = b2f(v[j][3] & 0xFFFF), f7 = b2f(v[j][3] >> 16);
                if (t == 0) {
                    a0[0] += f0; a0[1] += f1; a0[2] += f2; a0[3] += f3;
                    a0[4] += f4; a0[5] += f5; a0[6] += f6; a0[7] += f7;
                } else if (t == 1) {
                    a1[0] += f0; a1[1] += f1; a1[2] += f2; a1[3] += f3;
                    a1[4] += f4; a1[5] += f5; a1[6] += f6; a1[7] += f7;
                } else {
                    a2[0] += f0; a2[1] += f1; a2[2] += f2; a2[3] += f3;
                    a2[4] += f4; a2[5] += f5; a2[6] += f6; a2[7] += f7;
                }
            }
        }
        e += 8;
    }
    // pack + store: lane q writes dwords q*4..q*4+3 of each 64-dword type block
    unsigned int* dst = (unsigned int*)(aggb + (size_t)rnk[node] * AGGW);
    u32x4 o0 = { (unsigned int)f2b(a0[0]) | ((unsigned int)f2b(a0[1]) << 16),
                 (unsigned int)f2b(a0[2]) | ((unsigned int)f2b(a0[3]) << 16),
                 (unsigned int)f2b(a0[4]) | ((unsigned int)f2b(a0[5]) << 16),
                 (unsigned int)f2b(a0[6]) | ((unsigned int)f2b(a0[7]) << 16) };
    u32x4 o1 = { (unsigned int)f2b(a1[0]) | ((unsigned int)f2b(a1[1]) << 16),
                 (unsigned int)f2b(a1[2]) | ((unsigned int)f2b(a1[3]) << 16),
                 (unsigned int)f2b(a1[4]) | ((unsigned int)f2b(a1[5]) << 16),
                 (unsigned int)f2b(a1[6]) | ((unsigned int)f2b(a1[7]) << 16) };
    u32x4 o2 = { (unsigned int)f2b(a2[0]) | ((unsigned int)f2b(a2[1]) << 16),
                 (unsigned int)f2b(a2[2]) | ((unsigned int)f2b(a2[3]) << 16),
                 (unsigned int)f2b(a2[4]) | ((unsigned int)f2b(a2[5]) << 16),
                 (unsigned int)f2b(a2[6]) | ((unsigned int)f2b(a2[7]) << 16) };
    ((u32x4*)dst)[q]        = o0;
    ((u32x4*)(dst + 64))[q] = o1;
    ((u32x4*)(dst + 128))[q] = o2;
}

// ---------------- K6: node updater GEMM — sorted aggb => contiguous A-gather ----------------
__global__ __launch_bounds__(256, 3) void k_node(const float* __restrict__ nf,
        const unsigned short* __restrict__ nfb, const unsigned short* __restrict__ Wnb,
        const float* __restrict__ bn, const int* __restrict__ sn,
        const int* __restrict__ cnts, const unsigned short* __restrict__ aggb,
        float* __restrict__ out) {
    __shared__ unsigned short Wsm[CB][LDK2];
    int c0 = cnts[6], c1 = cnts[7], c2 = cnts[8];
    int n0 = (c0 + EM - 1) / EM, n1 = (c1 + EM - 1) / EM, n2 = (c2 + EM - 1) / EM;
    int ntile = n0 + n1 + n2;
    int b = blockIdx.x;
    int rt = (b & 7) * (NTILE_PAD / 8) + (b >> 3);   // bijective XCD swizzle (grid == NTILE_PAD)
    if (rt >= ntile) return;                          // uniform early exit (before any barrier)
    int tid = threadIdx.x;
    int wave = tid >> 6, l = tid & 63, lr = l & 15, kg = l >> 4;
    int t, tile;
    if (rt < n0) { t = 0; tile = rt; }
    else if (rt < n0 + n1) { t = 1; tile = rt - n0; }
    else { t = 2; tile = rt - n0 - n1; }
    int off = (t == 0) ? 0 : (t == 1) ? c0 : c0 + c1;
    int cntt = (t == 0) ? c0 : (t == 1) ? c1 : c2;
    int base = off + tile * EM;
    int m = min(EM, cntt - tile * EM);

    // ---- gather A-fragments once. aggb is in sn order: Ag reads are block-contiguous ----
    int srtrow = base + min(wave * 16 + lr, m - 1);
    int myrow = sn[srtrow];
    const u16x8* An = (const u16x8*)(nfb + (size_t)myrow * DD);
    const u16x8* Ag = (const u16x8*)(aggb + (size_t)srtrow * AGGW);
    u16x8 afr[16];
#pragma unroll
    for (int kc = 0; kc < 4; ++kc) {
#pragma unroll
        for (int k0 = 0; k0 < DD; k0 += 32) {
            u16x8 araw;
            if (kc == 0) {
                araw = An[(k0 >> 3) + kg];
#pragma unroll
                for (int j = 0; j < 8; ++j)
                    araw[j] = (araw[j] & 0x8000) ? (unsigned short)0 : araw[j];  // relu(nf)
            } else {
                araw = Ag[((kc - 1) * DD + k0) / 8 + kg];
            }
            afr[kc * 4 + (k0 >> 5)] = araw;   // static index (full unroll) -> stays in VGPRs
        }
    }

    // per-lane epilogue rows, hoisted out of the col-block loop
    int nd[4];
#pragma unroll
    for (int r = 0; r < 4; ++r) nd[r] = sn[base + min(wave * 16 + kg * 4 + r, m - 1)];

    int srow = tid & 31, scc = (tid >> 5) * 64;
#pragma unroll 1
    for (int cbk = 0; cbk < 4; ++cbk) {
        if (cbk) __syncthreads();          // drain Wsm readers of previous panel
        const u16x8* src = (const u16x8*)(Wnb + ((size_t)t * DD + cbk * CB + srow) * 512 + scc);
#pragma unroll
        for (int v = 0; v < 8; ++v) *(u16x8*)&Wsm[srow][scc + v * 8] = src[v];
        __syncthreads();

        f32x4 acc0 = {0.f, 0.f, 0.f, 0.f}, acc1 = {0.f, 0.f, 0.f, 0.f};
#pragma unroll
        for (int kc = 0; kc < 4; ++kc) {
#pragma unroll
            for (int k0 = 0; k0 < DD; k0 += 32) {
                bf16x8 a = __builtin_bit_cast(bf16x8, afr[kc * 4 + (k0 >> 5)]);
                int kw = kc * DD + k0 + kg * 8;
                bf16x8 b0 = *(const bf16x8*)&Wsm[lr][kw];
                bf16x8 b1 = *(const bf16x8*)&Wsm[16 + lr][kw];
                acc0 = __builtin_amdgcn_mfma_f32_16x16x32_bf16(a, b0, acc0, 0, 0, 0);
                acc1 = __builtin_amdgcn_mfma_f32_16x16x32_bf16(a, b1, acc1, 0, 0, 0);
            }
        }
#pragma unroll
        for (int n = 0; n < 2; n++) {
            int col = cbk * CB + n * 16 + lr;
            float bias = bn[t * DD + col];
            const f32x4& av = n ? acc1 : acc0;
#pragma unroll
            for (int r = 0; r < 4; r++) {
                int row = wave * 16 + kg * 4 + r;
                if (row < m) {
                    int node = nd[r];
                    out[(size_t)node * DD + col] = av[r] + bias + nf[(size_t)node * DD + col];
                }
            }
        }
    }
}

extern "C" void kernel_launch(void* const* d_in, const int* in_sizes, int n_in,
                              void* d_out, int out_size, void* d_ws, size_t ws_size,
                              hipStream_t stream) {
    const float* nf   = (const float*)d_in[0];
    const float* We   = (const float*)d_in[1];
    const float* be   = (const float*)d_in[2];
    const float* Wn   = (const float*)d_in[3];
    const float* bn   = (const float*)d_in[4];
    const int*   esrc = (const int*)d_in[5];
    const int*   edst = (const int*)d_in[6];
    const int*   et   = (const int*)d_in[7];
    const int*   ntp  = (const int*)d_in[8];
    float* out = (float*)d_out;

    // workspace carve-up
    char* w = (char*)d_ws;
    unsigned short* M    = (unsigned short*)w;  w += (size_t)NT * NN * DD * 2;    // 38.4 MB
    unsigned short* aggb = (unsigned short*)w;  w += (size_t)NN * AGGW * 2;       // 38.4 MB
    unsigned short* nfb  = (unsigned short*)w;  w += (size_t)NN * DD * 2;         // 12.8 MB
    unsigned short* Web  = (unsigned short*)w;  w += (size_t)NT * DD * DD * 2;    // 96 KB
    unsigned short* Wnb  = (unsigned short*)w;  w += (size_t)NT * DD * 512 * 2;   // 384 KB
    int* pe     = (int*)w;  w += (size_t)NE * 4;                                  // 3.2 MB
    int* rowcnt = (int*)w;  w += (size_t)NN * 4;                                  // 200 KB
    int* rowptr = (int*)w;  w += (size_t)(NN + 1) * 4;
    int* rowcur = (int*)w;  w += (size_t)NN * 4;
    int* sn     = (int*)w;  w += (size_t)NN * 4;
    int* rnk    = (int*)w;  w += (size_t)NN * 4;
    int* cnts   = (int*)w;  w += 16 * 4;

    const int NEB = (NE + EPB - 1) / EPB;      // 391
    const int NCH2 = (NN + 511) / 512;         // 98
    const int TILES2 = (NN + EM2 - 1) / EM2;   // 391 k_msg tiles

    k_prep<<<1024, 256, 0, stream>>>(nf, We, Wn, nfb, Web, Wnb, rowcnt, cnts);
    k_hist<<<256, 256, 0, stream>>>(edst, ntp, rowcnt, cnts);
    k_scan<<<1, 1024, 0, stream>>>(rowcnt, rowptr, rowcur);
    k_mid<<<NEB + NCH2 + NT * TILES2, 512, 0, stream>>>(nfb, Web, be, M,
            esrc, edst, et, ntp, rowcur, cnts, pe, sn, rnk);
    k_agg<<<NN / 8, 128, 0, stream>>>(M, rowptr, pe, rnk, aggb);
    k_node<<<NTILE_PAD, 256, 0, stream>>>(nf, nfb, Wnb, bn, sn, cnts, aggb, out);
}

// Round 11
// 196.116 us; speedup vs baseline: 1.5526x; 1.5526x over previous
//
#include <hip/hip_runtime.h>
#include <hip/hip_bf16.h>

#define NN 50000
#define NE 800000
#define DD 128
#define NT 3
#define AGGW 384           // T*D mailbox columns per node
#define EM 64              // rows per k_node GEMM tile
#define EM2 128            // rows per k_msg GEMM tile
#define LDK 136            // padded LDS row (bf16 elems) for k_msg W tile
#define CB 32              // k_node: output cols per W-panel stage
#define LDK2 520           // k_node: padded K-row (512+8)
#define EPB 2048           // edges per scatter block (391 blocks)
#define NTILES_MAX (((NN + EM - 1) / EM) + NT)      // 785 worst-case row tiles
#define NTILE_PAD (((NTILES_MAX + 7) / 8) * 8)      // 792, padded for XCD swizzle
#define NB1 ((NN + 1023) / 1024)                    // 49 scan blocks

typedef __bf16 bf16x8 __attribute__((ext_vector_type(8)));
typedef float f32x4 __attribute__((ext_vector_type(4)));
typedef unsigned short u16x8 __attribute__((ext_vector_type(8)));
typedef unsigned int u32x4 __attribute__((ext_vector_type(4)));

__device__ __forceinline__ unsigned short f2b(float f) {
    __hip_bfloat16 h = __float2bfloat16(f);
    return __builtin_bit_cast(unsigned short, h);
}
__device__ __forceinline__ float b2f(unsigned int u16bits) {
    unsigned int x = u16bits << 16;
    return __builtin_bit_cast(float, x);
}

// ---------------- K0: pre-convert f32 -> bf16 (nf, We, Wn) + zero rowcnt/cnts ----------------
__global__ void k_prep(const float* __restrict__ nf, const float* __restrict__ We,
                       const float* __restrict__ Wn, unsigned short* __restrict__ nfb,
                       unsigned short* __restrict__ Web, unsigned short* __restrict__ Wnb,
                       int* __restrict__ rowcnt, int* __restrict__ cnts) {
    size_t i = (size_t)blockIdx.x * blockDim.x + threadIdx.x;
    if (i < NN) rowcnt[i] = 0;
    if (i >= NN && i < NN + 16) cnts[i - NN] = 0;
    const size_t n0 = (size_t)NN * DD / 8;
    const size_t n1 = (size_t)NT * DD * DD / 8;
    const size_t n2 = (size_t)NT * DD * 512 / 8;
    size_t total = n0 + n1 + n2;
    for (size_t p = i; p < total; p += (size_t)gridDim.x * blockDim.x) {
        const float* s; unsigned short* d; size_t off;
        if (p < n0)            { s = nf; d = nfb; off = p; }
        else if (p < n0 + n1)  { s = We; d = Web; off = p - n0; }
        else                   { s = Wn; d = Wnb; off = p - n0 - n1; }
        const float4* f4 = (const float4*)(s + off * 8);
        float4 x = f4[0], y = f4[1];
        u16x8 u = { f2b(x.x), f2b(x.y), f2b(x.z), f2b(x.w),
                    f2b(y.x), f2b(y.y), f2b(y.z), f2b(y.w) };
        *(u16x8*)(d + off * 8) = u;
    }
}

// ---------------- K1: per-node degree histogram (direct global atomics) + node-type hist ----
__global__ __launch_bounds__(256) void k_hist(const int* __restrict__ edst,
        const int* __restrict__ ntp, int* __restrict__ rowcnt, int* __restrict__ cnts) {
    __shared__ int ln[3];
    int tid = threadIdx.x;
    if (tid < 3) ln[tid] = 0;
    __syncthreads();
    int i0 = blockIdx.x * 256 + tid;
    int stride = gridDim.x * 256;
    for (int p = i0; p < NE; p += stride) atomicAdd(&rowcnt[edst[p]], 1);
    for (int p = i0; p < NN; p += stride) atomicAdd(&ln[ntp[p]], 1);
    __syncthreads();
    if (tid < 3) atomicAdd(&cnts[6 + tid], ln[tid]);
}

// ---------------- K2a: per-block coalesced scan (one element/thread) ----------------
// R10's single-block chunked scan was 125us (stride-49 uncoalesced, 0.15% occupancy).
// This is the textbook 3-stage scan: every load lane-contiguous, 49 blocks in flight.
__global__ __launch_bounds__(1024) void k_scan1(const int* __restrict__ rowcnt,
        int* __restrict__ rowptr, int* __restrict__ bsum) {
    __shared__ int ws[16];
    int b = blockIdx.x, tid = threadIdx.x;
    int g = b * 1024 + tid;
    int v = (g < NN) ? rowcnt[g] : 0;
    int lane = tid & 63, wv = tid >> 6;
    int inc = v;
    for (int d = 1; d < 64; d <<= 1) { int u = __shfl_up(inc, d); if (lane >= d) inc += u; }
    if (lane == 63) ws[wv] = inc;
    __syncthreads();
    if (wv == 0 && lane < 16) {
        int wsv = ws[lane];
        int w2 = wsv;
        for (int d = 1; d < 16; d <<= 1) { int u = __shfl_up(w2, d); if (lane >= d) w2 += u; }
        ws[lane] = w2 - wsv;                 // exclusive wave base
        if (lane == 15) bsum[b] = w2;        // block total
    }
    __syncthreads();
    if (g < NN) rowptr[g] = inc - v + ws[wv];   // intra-block exclusive prefix
}

// ---------------- K2b: scan 49 block sums -> exclusive bases (in place) ----------------
__global__ void k_scan2(int* __restrict__ bsum) {
    int lane = threadIdx.x;
    int v = (lane < NB1) ? bsum[lane] : 0;
    int inc = v;
    for (int d = 1; d < 64; d <<= 1) { int u = __shfl_up(inc, d); if (lane >= d) inc += u; }
    if (lane < NB1) bsum[lane] = inc - v;
}

// ---------------- K2c: add block bases -> final rowptr, rowcur ----------------
__global__ __launch_bounds__(1024) void k_scan3(const int* __restrict__ bsum,
        int* __restrict__ rowptr, int* __restrict__ rowcur) {
    int b = blockIdx.x, g = b * 1024 + threadIdx.x;
    if (g < NN) {
        int p = rowptr[g] + bsum[b];
        rowptr[g] = p;
        rowcur[g] = p;
    }
    if (g == 0) rowptr[NN] = NE;
}

// ---------------- K3: MERGED direct scatter + node-type sort + message GEMM ----------------
// payload: rowid = t*NN+src (18b) | t<<25 (2b)
__global__ __launch_bounds__(512) void k_mid(
        const unsigned short* __restrict__ nfb, const unsigned short* __restrict__ Web,
        const float* __restrict__ be, unsigned short* __restrict__ M,
        const int* __restrict__ esrc, const int* __restrict__ edst,
        const int* __restrict__ et, const int* __restrict__ ntp,
        int* __restrict__ rowcur, int* __restrict__ cnts,
        int* __restrict__ pe, int* __restrict__ sn, int* __restrict__ rnk) {
    const int NEB = (NE + EPB - 1) / EPB;    // 391 edge-scatter blocks
    const int NCH2 = (NN + 511) / 512;       // 98 node-type blocks
    const int TILES = (NN + EM2 - 1) / EM2;  // 391 msg tiles per type
    __shared__ unsigned short Wsm[DD][LDK];  // 34 KB (msg role; tiny alias for role 2)
    int tid = threadIdx.x, b = blockIdx.x;

    if (b < NEB) {                           // ---- role 1: direct scatter (no LDS) ----
        int e0 = b * EPB;
#pragma unroll
        for (int i = 0; i < EPB; i += 512) {
            int e = e0 + i + tid;
            if (e < NE) {
                int d = edst[e];
                int t = et[e];
                int pos = atomicAdd(&rowcur[d], 1);
                pe[pos] = (t * NN + esrc[e]) | (t << 25);
            }
        }
    } else if (b < NEB + NCH2) {             // ---- role 2: node-type sort (512 thr) ----
        int* lcnt = (int*)&Wsm[0][0];
        int* lbase = lcnt + 4;
        if (tid < 3) lcnt[tid] = 0;
        __syncthreads();
        int p = (b - NEB) * 512 + tid;
        int t = -1, rank = 0;
        if (p < NN) { t = ntp[p]; rank = atomicAdd(&lcnt[t], 1); }
        __syncthreads();
        if (tid < 3) lbase[tid] = atomicAdd(&cnts[9 + tid], lcnt[tid]);
        __syncthreads();
        if (p < NN) {
            int c0 = cnts[6], c1 = cnts[7];
            int off = (t == 0) ? 0 : (t == 1) ? c0 : c0 + c1;
            int pos = off + lbase[t] + rank;
            sn[pos] = p;
            rnk[p] = pos;                    // inverse permutation for sorted aggb
        }
    } else {                                 // ---- role 3: message GEMM (512 thr) ----
        int bb = b - NEB - NCH2;
        int t = bb / TILES, tile = bb % TILES;
        int base = tile * EM2;
        int m = min(EM2, NN - base);
        { // stage Web[t] 128x128: 512 thr x 32 cols
            int row = tid >> 2, c0 = (tid & 3) * 32;
            const u16x8* src = (const u16x8*)(Web + ((size_t)t * DD + row) * DD + c0);
#pragma unroll
            for (int v = 0; v < 4; ++v) *(u16x8*)&Wsm[row][c0 + v * 8] = src[v];
        }
        __syncthreads();

        int wave = tid >> 6, l = tid & 63, lr2 = l & 15, kg = l >> 4;
        int arow = min(base + wave * 16 + lr2, NN - 1);
        const u16x8* Arow = (const u16x8*)(nfb + (size_t)arow * DD);
        f32x4 acc[8];
#pragma unroll
        for (int n = 0; n < 8; n++) acc[n] = (f32x4){0.f, 0.f, 0.f, 0.f};
#pragma unroll
        for (int k0 = 0; k0 < DD; k0 += 32) {
            bf16x8 a = __builtin_bit_cast(bf16x8, Arow[(k0 >> 3) + kg]);
#pragma unroll
            for (int n = 0; n < 8; n++) {
                bf16x8 bbv = *(const bf16x8*)&Wsm[n * 16 + lr2][k0 + kg * 8];
                acc[n] = __builtin_amdgcn_mfma_f32_16x16x32_bf16(a, bbv, acc[n], 0, 0, 0);
            }
        }
        unsigned short* Mt = M + (size_t)t * NN * DD;
#pragma unroll
        for (int n = 0; n < 8; n++) {
            int col = n * 16 + lr2;
            float bias = be[t * DD + col];
#pragma unroll
            for (int r = 0; r < 4; r++) {
                int row = wave * 16 + kg * 4 + r;
                if (row < m) {
                    float v = acc[n][r] + bias;
                    Mt[(size_t)(base + row) * DD + col] = f2b(fmaxf(v, 0.f));
                }
            }
        }
    }
}

// ---------------- K5: gather-reduce, one 16-lane group per node ----------------
// CLOSED at its DRAM-random floor (R3/R4/R5: 38-40us, FETCH pinned at 95 MB).
__global__ __launch_bounds__(128) void k_agg(const unsigned short* __restrict__ M,
        const int* __restrict__ rowptr, const int* __restrict__ pe,
        const int* __restrict__ rnk, unsigned short* __restrict__ aggb) {
    int node = blockIdx.x * 8 + (threadIdx.x >> 4);     // NN = 6250*8 exactly
    int q = threadIdx.x & 15;                           // lane within group: cols q*8..q*8+7
    int beg = rowptr[node], end = rowptr[node + 1];
    const u32x4* Mu4 = (const u32x4*)M;                 // one M row = 16 u32x4
    float a0[8] = {0,0,0,0,0,0,0,0};
    float a1[8] = {0,0,0,0,0,0,0,0};
    float a2[8] = {0,0,0,0,0,0,0,0};
    int e = beg;
    while (e < end) {                                   // trip count uniform within group
        unsigned int p[8];
        u32x4 v[8];
#pragma unroll
        for (int j = 0; j < 8; ++j) p[j] = pe[min(e + j, end - 1)];
#pragma unroll
        for (int j = 0; j < 8; ++j)
            if (e + j < end) v[j] = Mu4[(size_t)(p[j] & 0x3FFFFu) * 16 + q];
#pragma unroll
        for (int j = 0; j < 8; ++j) {
            if (e + j < end) {
                int t = p[j] >> 25;
                float f0 = b2f(v[j][0] & 0xFFFF), f1 = b2f(v[j][0] >> 16);
                float f2 = b2f(v[j][1] & 0xFFFF), f3 = b2f(v[j][1] >> 16);
                float f4 = b2f(v[j][2] & 0xFFFF), f5 = b2f(v[j][2] >> 16);
                float f6 = b2f(v[j][3] & 0xFFFF), f7 = b2f(v[j][3] >> 16);
                if (t == 0) {
                    a0[0] += f0; a0[1] += f1; a0[2] += f2; a0[3] += f3;
                    a0[4] += f4; a0[5] += f5; a0[6] += f6; a0[7] += f7;
                } else if (t == 1) {
                    a1[0] += f0; a1[1] += f1; a1[2] += f2; a1[3] += f3;
                    a1[4] += f4; a1[5] += f5; a1[6] += f6; a1[7] += f7;
                } else {
                    a2[0] += f0; a2[1] += f1; a2[2] += f2; a2[3] += f3;
                    a2[4] += f4; a2[5] += f5; a2[6] += f6; a2[7] += f7;
                }
            }
        }
        e += 8;
    }
    // pack + store: lane q writes dwords q*4..q*4+3 of each 64-dword type block
    unsigned int* dst = (unsigned int*)(aggb + (size_t)rnk[node] * AGGW);
    u32x4 o0 = { (unsigned int)f2b(a0[0]) | ((unsigned int)f2b(a0[1]) << 16),
                 (unsigned int)f2b(a0[2]) | ((unsigned int)f2b(a0[3]) << 16),
                 (unsigned int)f2b(a0[4]) | ((unsigned int)f2b(a0[5]) << 16),
                 (unsigned int)f2b(a0[6]) | ((unsigned int)f2b(a0[7]) << 16) };
    u32x4 o1 = { (unsigned int)f2b(a1[0]) | ((unsigned int)f2b(a1[1]) << 16),
                 (unsigned int)f2b(a1[2]) | ((unsigned int)f2b(a1[3]) << 16),
                 (unsigned int)f2b(a1[4]) | ((unsigned int)f2b(a1[5]) << 16),
                 (unsigned int)f2b(a1[6]) | ((unsigned int)f2b(a1[7]) << 16) };
    u32x4 o2 = { (unsigned int)f2b(a2[0]) | ((unsigned int)f2b(a2[1]) << 16),
                 (unsigned int)f2b(a2[2]) | ((unsigned int)f2b(a2[3]) << 16),
                 (unsigned int)f2b(a2[4]) | ((unsigned int)f2b(a2[5]) << 16),
                 (unsigned int)f2b(a2[6]) | ((unsigned int)f2b(a2[7]) << 16) };
    ((u32x4*)dst)[q]        = o0;
    ((u32x4*)(dst + 64))[q] = o1;
    ((u32x4*)(dst + 128))[q] = o2;
}

// ---------------- K6: node updater GEMM — sorted aggb => contiguous A-gather ----------------
__global__ __launch_bounds__(256, 3) void k_node(const float* __restrict__ nf,
        const unsigned short* __restrict__ nfb, const unsigned short* __restrict__ Wnb,
        const float* __restrict__ bn, const int* __restrict__ sn,
        const int* __restrict__ cnts, const unsigned short* __restrict__ aggb,
        float* __restrict__ out) {
    __shared__ unsigned short Wsm[CB][LDK2];
    int c0 = cnts[6], c1 = cnts[7], c2 = cnts[8];
    int n0 = (c0 + EM - 1) / EM, n1 = (c1 + EM - 1) / EM, n2 = (c2 + EM - 1) / EM;
    int ntile = n0 + n1 + n2;
    int b = blockIdx.x;
    int rt = (b & 7) * (NTILE_PAD / 8) + (b >> 3);   // bijective XCD swizzle (grid == NTILE_PAD)
    if (rt >= ntile) return;                          // uniform early exit (before any barrier)
    int tid = threadIdx.x;
    int wave = tid >> 6, l = tid & 63, lr = l & 15, kg = l >> 4;
    int t, tile;
    if (rt < n0) { t = 0; tile = rt; }
    else if (rt < n0 + n1) { t = 1; tile = rt - n0; }
    else { t = 2; tile = rt - n0 - n1; }
    int off = (t == 0) ? 0 : (t == 1) ? c0 : c0 + c1;
    int cntt = (t == 0) ? c0 : (t == 1) ? c1 : c2;
    int base = off + tile * EM;
    int m = min(EM, cntt - tile * EM);

    // ---- gather A-fragments once. aggb is in sn order: Ag reads are block-contiguous ----
    int srtrow = base + min(wave * 16 + lr, m - 1);
    int myrow = sn[srtrow];
    const u16x8* An = (const u16x8*)(nfb + (size_t)myrow * DD);
    const u16x8* Ag = (const u16x8*)(aggb + (size_t)srtrow * AGGW);
    u16x8 afr[16];
#pragma unroll
    for (int kc = 0; kc < 4; ++kc) {
#pragma unroll
        for (int k0 = 0; k0 < DD; k0 += 32) {
            u16x8 araw;
            if (kc == 0) {
                araw = An[(k0 >> 3) + kg];
#pragma unroll
                for (int j = 0; j < 8; ++j)
                    araw[j] = (araw[j] & 0x8000) ? (unsigned short)0 : araw[j];  // relu(nf)
            } else {
                araw = Ag[((kc - 1) * DD + k0) / 8 + kg];
            }
            afr[kc * 4 + (k0 >> 5)] = araw;   // static index (full unroll) -> stays in VGPRs
        }
    }

    // per-lane epilogue rows, hoisted out of the col-block loop
    int nd[4];
#pragma unroll
    for (int r = 0; r < 4; ++r) nd[r] = sn[base + min(wave * 16 + kg * 4 + r, m - 1)];

    int srow = tid & 31, scc = (tid >> 5) * 64;
#pragma unroll 1
    for (int cbk = 0; cbk < 4; ++cbk) {
        if (cbk) __syncthreads();          // drain Wsm readers of previous panel
        const u16x8* src = (const u16x8*)(Wnb + ((size_t)t * DD + cbk * CB + srow) * 512 + scc);
#pragma unroll
        for (int v = 0; v < 8; ++v) *(u16x8*)&Wsm[srow][scc + v * 8] = src[v];
        __syncthreads();

        f32x4 acc0 = {0.f, 0.f, 0.f, 0.f}, acc1 = {0.f, 0.f, 0.f, 0.f};
#pragma unroll
        for (int kc = 0; kc < 4; ++kc) {
#pragma unroll
            for (int k0 = 0; k0 < DD; k0 += 32) {
                bf16x8 a = __builtin_bit_cast(bf16x8, afr[kc * 4 + (k0 >> 5)]);
                int kw = kc * DD + k0 + kg * 8;
                bf16x8 b0 = *(const bf16x8*)&Wsm[lr][kw];
                bf16x8 b1 = *(const bf16x8*)&Wsm[16 + lr][kw];
                acc0 = __builtin_amdgcn_mfma_f32_16x16x32_bf16(a, b0, acc0, 0, 0, 0);
                acc1 = __builtin_amdgcn_mfma_f32_16x16x32_bf16(a, b1, acc1, 0, 0, 0);
            }
        }
#pragma unroll
        for (int n = 0; n < 2; n++) {
            int col = cbk * CB + n * 16 + lr;
            float bias = bn[t * DD + col];
            const f32x4& av = n ? acc1 : acc0;
#pragma unroll
            for (int r = 0; r < 4; r++) {
                int row = wave * 16 + kg * 4 + r;
                if (row < m) {
                    int node = nd[r];
                    out[(size_t)node * DD + col] = av[r] + bias + nf[(size_t)node * DD + col];
                }
            }
        }
    }
}

extern "C" void kernel_launch(void* const* d_in, const int* in_sizes, int n_in,
                              void* d_out, int out_size, void* d_ws, size_t ws_size,
                              hipStream_t stream) {
    const float* nf   = (const float*)d_in[0];
    const float* We   = (const float*)d_in[1];
    const float* be   = (const float*)d_in[2];
    const float* Wn   = (const float*)d_in[3];
    const float* bn   = (const float*)d_in[4];
    const int*   esrc = (const int*)d_in[5];
    const int*   edst = (const int*)d_in[6];
    const int*   et   = (const int*)d_in[7];
    const int*   ntp  = (const int*)d_in[8];
    float* out = (float*)d_out;

    // workspace carve-up
    char* w = (char*)d_ws;
    unsigned short* M    = (unsigned short*)w;  w += (size_t)NT * NN * DD * 2;    // 38.4 MB
    unsigned short* aggb = (unsigned short*)w;  w += (size_t)NN * AGGW * 2;       // 38.4 MB
    unsigned short* nfb  = (unsigned short*)w;  w += (size_t)NN * DD * 2;         // 12.8 MB
    unsigned short* Web  = (unsigned short*)w;  w += (size_t)NT * DD * DD * 2;    // 96 KB
    unsigned short* Wnb  = (unsigned short*)w;  w += (size_t)NT * DD * 512 * 2;   // 384 KB
    int* pe     = (int*)w;  w += (size_t)NE * 4;                                  // 3.2 MB
    int* rowcnt = (int*)w;  w += (size_t)NN * 4;                                  // 200 KB
    int* rowptr = (int*)w;  w += (size_t)(NN + 1) * 4;
    int* rowcur = (int*)w;  w += (size_t)NN * 4;
    int* sn     = (int*)w;  w += (size_t)NN * 4;
    int* rnk    = (int*)w;  w += (size_t)NN * 4;
    int* bsum   = (int*)w;  w += (NB1 + 1) * 4;
    int* cnts   = (int*)w;  w += 16 * 4;

    const int NEB = (NE + EPB - 1) / EPB;      // 391
    const int NCH2 = (NN + 511) / 512;         // 98
    const int TILES2 = (NN + EM2 - 1) / EM2;   // 391 k_msg tiles

    k_prep<<<1024, 256, 0, stream>>>(nf, We, Wn, nfb, Web, Wnb, rowcnt, cnts);
    k_hist<<<256, 256, 0, stream>>>(edst, ntp, rowcnt, cnts);
    k_scan1<<<NB1, 1024, 0, stream>>>(rowcnt, rowptr, bsum);
    k_scan2<<<1, 64, 0, stream>>>(bsum);
    k_scan3<<<NB1, 1024, 0, stream>>>(bsum, rowptr, rowcur);
    k_mid<<<NEB + NCH2 + NT * TILES2, 512, 0, stream>>>(nfb, Web, be, M,
            esrc, edst, et, ntp, rowcur, cnts, pe, sn, rnk);
    k_agg<<<NN / 8, 128, 0, stream>>>(M, rowptr, pe, rnk, aggb);
    k_node<<<NTILE_PAD, 256, 0, stream>>>(nf, nfb, Wnb, bn, sn, cnts, aggb, out);
}

// Round 12
// 129.226 us; speedup vs baseline: 2.3563x; 1.5176x over previous
//
#include <hip/hip_runtime.h>
#include <hip/hip_bf16.h>

#define NN 50000
#define NE 800000
#define DD 128
#define NT 3
#define AGGW 384           // T*D mailbox columns per node
#define EM 64              // rows per k_node GEMM tile
#define EM2 128            // rows per k_msg GEMM tile
#define LDK 136            // padded LDS row (bf16 elems) for k_msg W tile
#define CB 32              // k_node: output cols per W-panel stage
#define LDK2 520           // k_node: padded K-row (512+8)
#define NBITS 7            // bin = dst >> 7 (128 nodes/bin)
#define NBINS ((NN + 127) / 128)   // 391
#define EPB 8192           // edges per scatter block (98 blocks; run len ~21 edges/bin
                           // = 84B write runs -> 4x less pe write-amp vs EPB=2048)
#define BINCAP 2560        // max edges/bin in k_binsort LDS (lambda=2046, +11 sigma)
#define NTILES_MAX (((NN + EM - 1) / EM) + NT)      // 785 worst-case row tiles
#define NTILE_PAD (((NTILES_MAX + 7) / 8) * 8)      // 792, padded for XCD swizzle

typedef __bf16 bf16x8 __attribute__((ext_vector_type(8)));
typedef float f32x4 __attribute__((ext_vector_type(4)));
typedef unsigned short u16x8 __attribute__((ext_vector_type(8)));
typedef unsigned int u32x4 __attribute__((ext_vector_type(4)));

__device__ __forceinline__ unsigned short f2b(float f) {
    __hip_bfloat16 h = __float2bfloat16(f);
    return __builtin_bit_cast(unsigned short, h);
}
__device__ __forceinline__ float b2f(unsigned int u16bits) {
    unsigned int x = u16bits << 16;
    return __builtin_bit_cast(float, x);
}

// ---------------- K0: pre-convert f32 -> bf16 (nf, We, Wn) + zero bhist/cnts ----------------
__global__ void k_prep(const float* __restrict__ nf, const float* __restrict__ We,
                       const float* __restrict__ Wn, unsigned short* __restrict__ nfb,
                       unsigned short* __restrict__ Web, unsigned short* __restrict__ Wnb,
                       int* __restrict__ bhist, int* __restrict__ cnts) {
    size_t i = (size_t)blockIdx.x * blockDim.x + threadIdx.x;
    if (i < NBINS) bhist[i] = 0;
    if (i >= NBINS && i < NBINS + 16) cnts[i - NBINS] = 0;
    const size_t n0 = (size_t)NN * DD / 8;
    const size_t n1 = (size_t)NT * DD * DD / 8;
    const size_t n2 = (size_t)NT * DD * 512 / 8;
    size_t total = n0 + n1 + n2;
    for (size_t p = i; p < total; p += (size_t)gridDim.x * blockDim.x) {
        const float* s; unsigned short* d; size_t off;
        if (p < n0)            { s = nf; d = nfb; off = p; }
        else if (p < n0 + n1)  { s = We; d = Web; off = p - n0; }
        else                   { s = Wn; d = Wnb; off = p - n0 - n1; }
        const float4* f4 = (const float4*)(s + off * 8);
        float4 x = f4[0], y = f4[1];
        u16x8 u = { f2b(x.x), f2b(x.y), f2b(x.z), f2b(x.w),
                    f2b(y.x), f2b(y.y), f2b(y.z), f2b(y.w) };
        *(u16x8*)(d + off * 8) = u;
    }
}

// ---------------- K1: bin histogram (LDS-aggregated) + node-type histogram ----------------
__global__ __launch_bounds__(256) void k_binhist(const int* __restrict__ edst,
        const int* __restrict__ ntp, int* __restrict__ bhist, int* __restrict__ cnts) {
    __shared__ int lh[NBINS];
    __shared__ int ln[3];
    int tid = threadIdx.x;
    for (int i = tid; i < NBINS; i += 256) lh[i] = 0;
    if (tid < 3) ln[tid] = 0;
    __syncthreads();
    int i0 = blockIdx.x * blockDim.x + tid;
    int stride = gridDim.x * blockDim.x;
    for (int p = i0; p < NE; p += stride) atomicAdd(&lh[edst[p] >> NBITS], 1);
    for (int p = i0; p < NN; p += stride) atomicAdd(&ln[ntp[p]], 1);
    __syncthreads();
    for (int i = tid; i < NBINS; i += 256) if (lh[i]) atomicAdd(&bhist[i], lh[i]);
    if (tid < 3) atomicAdd(&cnts[6 + tid], ln[tid]);
}

// ---------------- K2: scan 391 bins -> binptr, bincur (single block) ----------------
__global__ __launch_bounds__(512) void k_binscan(const int* __restrict__ bhist,
        int* __restrict__ binptr, int* __restrict__ bincur, int* __restrict__ rowptr) {
    __shared__ int sa[NBINS], sb[NBINS];
    int tid = threadIdx.x;
    if (tid < NBINS) sa[tid] = bhist[tid];
    __syncthreads();
    int flip = 0;
    for (int off = 1; off < NBINS; off <<= 1) {
        int* src = flip ? sb : sa;
        int* dst = flip ? sa : sb;
        if (tid < NBINS) dst[tid] = src[tid] + ((tid >= off) ? src[tid - off] : 0);
        __syncthreads();
        flip ^= 1;
    }
    int* inc = flip ? sb : sa;   // inclusive scan
    if (tid < NBINS) {
        int excl = (tid == 0) ? 0 : inc[tid - 1];
        binptr[tid] = excl;
        bincur[tid] = excl;
    }
    if (tid == 0) { binptr[NBINS] = NE; rowptr[NN] = NE; }
}

// ---------------- K3: MERGED binned scatter + node-type sort + message GEMM ----------------
// R11 post-mortem: direct per-edge atomic scatter = 76us (WRITE 94MB, random 4B stores).
// The binned 3-phase scatter exists for WRITE-LOCALITY; reverted to it, with EPB=8192 so
// each (block,bin) run is ~21 edges (~84B consecutive) -> ~4x less pe write-amp and 4x
// fewer bincur atomics than the 42.6us EPB=2048 version.
// payload: rowid = t*NN+src (18b) | dstlo<<18 (7b) | t<<25 (2b)
__global__ __launch_bounds__(512) void k_mid(
        const unsigned short* __restrict__ nfb, const unsigned short* __restrict__ Web,
        const float* __restrict__ be, unsigned short* __restrict__ M,
        const int* __restrict__ esrc, const int* __restrict__ edst,
        const int* __restrict__ et, const int* __restrict__ ntp,
        int* __restrict__ bincur, int* __restrict__ cnts,
        int* __restrict__ pe, int* __restrict__ sn, int* __restrict__ rnk) {
    const int NEB = (NE + EPB - 1) / EPB;    // 98 edge-scatter blocks
    const int NCH2 = (NN + 511) / 512;       // 98 node-type blocks
    const int TILES = (NN + EM2 - 1) / EM2;  // 391 msg tiles per type
    __shared__ unsigned short Wsm[DD][LDK];  // 34 KB (aliased below)
    int tid = threadIdx.x, b = blockIdx.x;

    if (b < NEB) {                           // ---- role 1: binned scatter (3 phases) ----
        int* lh = (int*)&Wsm[0][0];
        int* gb = lh + NBINS;
        int* lr = gb + NBINS;
        for (int i = tid; i < NBINS; i += 512) { lh[i] = 0; lr[i] = 0; }
        __syncthreads();
        int e0 = b * EPB;
#pragma unroll
        for (int i = 0; i < EPB; i += 512) {
            int e = e0 + i + tid;
            if (e < NE) atomicAdd(&lh[edst[e] >> NBITS], 1);
        }
        __syncthreads();
        for (int i = tid; i < NBINS; i += 512)
            if (lh[i]) gb[i] = atomicAdd(&bincur[i], lh[i]);
        __syncthreads();
#pragma unroll
        for (int i = 0; i < EPB; i += 512) {
            int e = e0 + i + tid;
            if (e < NE) {
                int d = edst[e];
                int t = et[e];
                int bin = d >> NBITS;
                int rank = atomicAdd(&lr[bin], 1);
                pe[gb[bin] + rank] = (t * NN + esrc[e]) | ((d & 127) << 18) | (t << 25);
            }
        }
    } else if (b < NEB + NCH2) {             // ---- role 2: node-type sort (512 thr) ----
        int* lcnt = (int*)&Wsm[0][0];
        int* lbase = lcnt + 4;
        if (tid < 3) lcnt[tid] = 0;
        __syncthreads();
        int p = (b - NEB) * 512 + tid;
        int t = -1, rank = 0;
        if (p < NN) { t = ntp[p]; rank = atomicAdd(&lcnt[t], 1); }
        __syncthreads();
        if (tid < 3) lbase[tid] = atomicAdd(&cnts[9 + tid], lcnt[tid]);
        __syncthreads();
        if (p < NN) {
            int c0 = cnts[6], c1 = cnts[7];
            int off = (t == 0) ? 0 : (t == 1) ? c0 : c0 + c1;
            int pos = off + lbase[t] + rank;
            sn[pos] = p;
            rnk[p] = pos;                    // inverse permutation for sorted aggb
        }
    } else {                                 // ---- role 3: message GEMM (512 thr) ----
        int bb = b - NEB - NCH2;
        int t = bb / TILES, tile = bb % TILES;
        int base = tile * EM2;
        int m = min(EM2, NN - base);
        { // stage Web[t] 128x128: 512 thr x 32 cols
            int row = tid >> 2, c0 = (tid & 3) * 32;
            const u16x8* src = (const u16x8*)(Web + ((size_t)t * DD + row) * DD + c0);
#pragma unroll
            for (int v = 0; v < 4; ++v) *(u16x8*)&Wsm[row][c0 + v * 8] = src[v];
        }
        __syncthreads();

        int wave = tid >> 6, l = tid & 63, lr2 = l & 15, kg = l >> 4;
        int arow = min(base + wave * 16 + lr2, NN - 1);
        const u16x8* Arow = (const u16x8*)(nfb + (size_t)arow * DD);
        f32x4 acc[8];
#pragma unroll
        for (int n = 0; n < 8; n++) acc[n] = (f32x4){0.f, 0.f, 0.f, 0.f};
#pragma unroll
        for (int k0 = 0; k0 < DD; k0 += 32) {
            bf16x8 a = __builtin_bit_cast(bf16x8, Arow[(k0 >> 3) + kg]);
#pragma unroll
            for (int n = 0; n < 8; n++) {
                bf16x8 bbv = *(const bf16x8*)&Wsm[n * 16 + lr2][k0 + kg * 8];
                acc[n] = __builtin_amdgcn_mfma_f32_16x16x32_bf16(a, bbv, acc[n], 0, 0, 0);
            }
        }
        unsigned short* Mt = M + (size_t)t * NN * DD;
#pragma unroll
        for (int n = 0; n < 8; n++) {
            int col = n * 16 + lr2;
            float bias = be[t * DD + col];
#pragma unroll
            for (int r = 0; r < 4; r++) {
                int row = wave * 16 + kg * 4 + r;
                if (row < m) {
                    float v = acc[n][r] + bias;
                    Mt[(size_t)(base + row) * DD + col] = f2b(fmaxf(v, 0.f));
                }
            }
        }
    }
}

// ---------------- K3b: per-bin in-place counting sort by dstlo + rowptr emit (512 thr) ----
__global__ __launch_bounds__(512) void k_binsort(const int* __restrict__ binptr,
        int* __restrict__ pe, int* __restrict__ rowptr) {
    __shared__ int lcnt[128], lrk[128], lrp[128];
    __shared__ unsigned int sorted[BINCAP];
    int b = blockIdx.x, tid = threadIdx.x;
    int beg = binptr[b], end = binptr[b + 1];
    int cnt = min(end - beg, BINCAP);
    if (tid < 128) { lcnt[tid] = 0; lrk[tid] = 0; }
    __syncthreads();
    for (int e = tid; e < cnt; e += 512)
        atomicAdd(&lcnt[(pe[beg + e] >> 18) & 127], 1);
    __syncthreads();
    if (tid < 64) { // exclusive scan of 128 counters with one wave
        int v = lcnt[2 * tid] + lcnt[2 * tid + 1];
        int s = v;
        for (int d = 1; d < 64; d <<= 1) {
            int u = __shfl_up(s, d);
            if (tid >= d) s += u;
        }
        int excl = s - v;
        lrp[2 * tid] = excl;
        lrp[2 * tid + 1] = excl + lcnt[2 * tid];
    }
    __syncthreads();
    if (tid < 128) {
        int node = b * 128 + tid;
        if (node < NN) rowptr[node] = beg + lrp[tid];
    }
    for (int e = tid; e < cnt; e += 512) {
        unsigned int p = pe[beg + e];
        int d = (p >> 18) & 127;
        int pos = lrp[d] + atomicAdd(&lrk[d], 1);
        sorted[pos] = p;
    }
    __syncthreads();
    for (int e = tid; e < cnt; e += 512) pe[beg + e] = sorted[e];  // coalesced write-back
}

// ---------------- K5: gather-reduce, one 16-lane group per node ----------------
// CLOSED at its DRAM-random floor (R3/R4/R5: 38-40us, FETCH pinned at 95 MB).
__global__ __launch_bounds__(128) void k_agg(const unsigned short* __restrict__ M,
        const int* __restrict__ rowptr, const int* __restrict__ pe,
        const int* __restrict__ rnk, unsigned short* __restrict__ aggb) {
    int node = blockIdx.x * 8 + (threadIdx.x >> 4);     // NN = 6250*8 exactly
    int q = threadIdx.x & 15;                           // lane within group: cols q*8..q*8+7
    int beg = rowptr[node], end = rowptr[node + 1];
    const u32x4* Mu4 = (const u32x4*)M;                 // one M row = 16 u32x4
    float a0[8] = {0,0,0,0,0,0,0,0};
    float a1[8] = {0,0,0,0,0,0,0,0};
    float a2[8] = {0,0,0,0,0,0,0,0};
    int e = beg;
    while (e < end) {                                   // trip count uniform within group
        unsigned int p[8];
        u32x4 v[8];
#pragma unroll
        for (int j = 0; j < 8; ++j) p[j] = pe[min(e + j, end - 1)];
#pragma unroll
        for (int j = 0; j < 8; ++j)
            if (e + j < end) v[j] = Mu4[(size_t)(p[j] & 0x3FFFFu) * 16 + q];
#pragma unroll
        for (int j = 0; j < 8; ++j) {
            if (e + j < end) {
                int t = p[j] >> 25;
                float f0 = b2f(v[j][0] & 0xFFFF), f1 = b2f(v[j][0] >> 16);
                float f2 = b2f(v[j][1] & 0xFFFF), f3 = b2f(v[j][1] >> 16);
                float f4 = b2f(v[j][2] & 0xFFFF), f5 = b2f(v[j][2] >> 16);
                float f6 = b2f(v[j][3] & 0xFFFF), f7 = b2f(v[j][3] >> 16);
                if (t == 0) {
                    a0[0] += f0; a0[1] += f1; a0[2] += f2; a0[3] += f3;
                    a0[4] += f4; a0[5] += f5; a0[6] += f6; a0[7] += f7;
                } else if (t == 1) {
                    a1[0] += f0; a1[1] += f1; a1[2] += f2; a1[3] += f3;
                    a1[4] += f4; a1[5] += f5; a1[6] += f6; a1[7] += f7;
                } else {
                    a2[0] += f0; a2[1] += f1; a2[2] += f2; a2[3] += f3;
                    a2[4] += f4; a2[5] += f5; a2[6] += f6; a2[7] += f7;
                }
            }
        }
        e += 8;
    }
    // pack + store: lane q writes dwords q*4..q*4+3 of each 64-dword type block
    unsigned int* dst = (unsigned int*)(aggb + (size_t)rnk[node] * AGGW);
    u32x4 o0 = { (unsigned int)f2b(a0[0]) | ((unsigned int)f2b(a0[1]) << 16),
                 (unsigned int)f2b(a0[2]) | ((unsigned int)f2b(a0[3]) << 16),
                 (unsigned int)f2b(a0[4]) | ((unsigned int)f2b(a0[5]) << 16),
                 (unsigned int)f2b(a0[6]) | ((unsigned int)f2b(a0[7]) << 16) };
    u32x4 o1 = { (unsigned int)f2b(a1[0]) | ((unsigned int)f2b(a1[1]) << 16),
                 (unsigned int)f2b(a1[2]) | ((unsigned int)f2b(a1[3]) << 16),
                 (unsigned int)f2b(a1[4]) | ((unsigned int)f2b(a1[5]) << 16),
                 (unsigned int)f2b(a1[6]) | ((unsigned int)f2b(a1[7]) << 16) };
    u32x4 o2 = { (unsigned int)f2b(a2[0]) | ((unsigned int)f2b(a2[1]) << 16),
                 (unsigned int)f2b(a2[2]) | ((unsigned int)f2b(a2[3]) << 16),
                 (unsigned int)f2b(a2[4]) | ((unsigned int)f2b(a2[5]) << 16),
                 (unsigned int)f2b(a2[6]) | ((unsigned int)f2b(a2[7]) << 16) };
    ((u32x4*)dst)[q]        = o0;
    ((u32x4*)(dst + 64))[q] = o1;
    ((u32x4*)(dst + 128))[q] = o2;
}

// ---------------- K6: node updater GEMM — sorted aggb => contiguous A-gather ----------------
__global__ __launch_bounds__(256, 3) void k_node(const float* __restrict__ nf,
        const unsigned short* __restrict__ nfb, const unsigned short* __restrict__ Wnb,
        const float* __restrict__ bn, const int* __restrict__ sn,
        const int* __restrict__ cnts, const unsigned short* __restrict__ aggb,
        float* __restrict__ out) {
    __shared__ unsigned short Wsm[CB][LDK2];
    int c0 = cnts[6], c1 = cnts[7], c2 = cnts[8];
    int n0 = (c0 + EM - 1) / EM, n1 = (c1 + EM - 1) / EM, n2 = (c2 + EM - 1) / EM;
    int ntile = n0 + n1 + n2;
    int b = blockIdx.x;
    int rt = (b & 7) * (NTILE_PAD / 8) + (b >> 3);   // bijective XCD swizzle (grid == NTILE_PAD)
    if (rt >= ntile) return;                          // uniform early exit (before any barrier)
    int tid = threadIdx.x;
    int wave = tid >> 6, l = tid & 63, lr = l & 15, kg = l >> 4;
    int t, tile;
    if (rt < n0) { t = 0; tile = rt; }
    else if (rt < n0 + n1) { t = 1; tile = rt - n0; }
    else { t = 2; tile = rt - n0 - n1; }
    int off = (t == 0) ? 0 : (t == 1) ? c0 : c0 + c1;
    int cntt = (t == 0) ? c0 : (t == 1) ? c1 : c2;
    int base = off + tile * EM;
    int m = min(EM, cntt - tile * EM);

    // ---- gather A-fragments once. aggb is in sn order: Ag reads are block-contiguous ----
    int srtrow = base + min(wave * 16 + lr, m - 1);
    int myrow = sn[srtrow];
    const u16x8* An = (const u16x8*)(nfb + (size_t)myrow * DD);
    const u16x8* Ag = (const u16x8*)(aggb + (size_t)srtrow * AGGW);
    u16x8 afr[16];
#pragma unroll
    for (int kc = 0; kc < 4; ++kc) {
#pragma unroll
        for (int k0 = 0; k0 < DD; k0 += 32) {
            u16x8 araw;
            if (kc == 0) {
                araw = An[(k0 >> 3) + kg];
#pragma unroll
                for (int j = 0; j < 8; ++j)
                    araw[j] = (araw[j] & 0x8000) ? (unsigned short)0 : araw[j];  // relu(nf)
            } else {
                araw = Ag[((kc - 1) * DD + k0) / 8 + kg];
            }
            afr[kc * 4 + (k0 >> 5)] = araw;   // static index (full unroll) -> stays in VGPRs
        }
    }

    // per-lane epilogue rows, hoisted out of the col-block loop
    int nd[4];
#pragma unroll
    for (int r = 0; r < 4; ++r) nd[r] = sn[base + min(wave * 16 + kg * 4 + r, m - 1)];

    int srow = tid & 31, scc = (tid >> 5) * 64;
#pragma unroll 1
    for (int cbk = 0; cbk < 4; ++cbk) {
        if (cbk) __syncthreads();          // drain Wsm readers of previous panel
        const u16x8* src = (const u16x8*)(Wnb + ((size_t)t * DD + cbk * CB + srow) * 512 + scc);
#pragma unroll
        for (int v = 0; v < 8; ++v) *(u16x8*)&Wsm[srow][scc + v * 8] = src[v];
        __syncthreads();

        f32x4 acc0 = {0.f, 0.f, 0.f, 0.f}, acc1 = {0.f, 0.f, 0.f, 0.f};
#pragma unroll
        for (int kc = 0; kc < 4; ++kc) {
#pragma unroll
            for (int k0 = 0; k0 < DD; k0 += 32) {
                bf16x8 a = __builtin_bit_cast(bf16x8, afr[kc * 4 + (k0 >> 5)]);
                int kw = kc * DD + k0 + kg * 8;
                bf16x8 b0 = *(const bf16x8*)&Wsm[lr][kw];
                bf16x8 b1 = *(const bf16x8*)&Wsm[16 + lr][kw];
                acc0 = __builtin_amdgcn_mfma_f32_16x16x32_bf16(a, b0, acc0, 0, 0, 0);
                acc1 = __builtin_amdgcn_mfma_f32_16x16x32_bf16(a, b1, acc1, 0, 0, 0);
            }
        }
#pragma unroll
        for (int n = 0; n < 2; n++) {
            int col = cbk * CB + n * 16 + lr;
            float bias = bn[t * DD + col];
            const f32x4& av = n ? acc1 : acc0;
#pragma unroll
            for (int r = 0; r < 4; r++) {
                int row = wave * 16 + kg * 4 + r;
                if (row < m) {
                    int node = nd[r];
                    out[(size_t)node * DD + col] = av[r] + bias + nf[(size_t)node * DD + col];
                }
            }
        }
    }
}

extern "C" void kernel_launch(void* const* d_in, const int* in_sizes, int n_in,
                              void* d_out, int out_size, void* d_ws, size_t ws_size,
                              hipStream_t stream) {
    const float* nf   = (const float*)d_in[0];
    const float* We   = (const float*)d_in[1];
    const float* be   = (const float*)d_in[2];
    const float* Wn   = (const float*)d_in[3];
    const float* bn   = (const float*)d_in[4];
    const int*   esrc = (const int*)d_in[5];
    const int*   edst = (const int*)d_in[6];
    const int*   et   = (const int*)d_in[7];
    const int*   ntp  = (const int*)d_in[8];
    float* out = (float*)d_out;

    // workspace carve-up
    char* w = (char*)d_ws;
    unsigned short* M    = (unsigned short*)w;  w += (size_t)NT * NN * DD * 2;    // 38.4 MB
    unsigned short* aggb = (unsigned short*)w;  w += (size_t)NN * AGGW * 2;       // 38.4 MB
    unsigned short* nfb  = (unsigned short*)w;  w += (size_t)NN * DD * 2;         // 12.8 MB
    unsigned short* Web  = (unsigned short*)w;  w += (size_t)NT * DD * DD * 2;    // 96 KB
    unsigned short* Wnb  = (unsigned short*)w;  w += (size_t)NT * DD * 512 * 2;   // 384 KB
    int* pe     = (int*)w;  w += (size_t)NE * 4;                                  // 3.2 MB
    int* bhist  = (int*)w;  w += (NBINS + 1) * 4;
    int* binptr = (int*)w;  w += (NBINS + 1) * 4;
    int* bincur = (int*)w;  w += (NBINS + 1) * 4;
    int* rowptr = (int*)w;  w += (size_t)(NN + 1) * 4;
    int* sn     = (int*)w;  w += (size_t)NN * 4;
    int* rnk    = (int*)w;  w += (size_t)NN * 4;
    int* cnts   = (int*)w;  w += 16 * 4;

    const int NEB = (NE + EPB - 1) / EPB;      // 98
    const int NCH2 = (NN + 511) / 512;         // 98
    const int TILES2 = (NN + EM2 - 1) / EM2;   // 391 k_msg tiles

    k_prep<<<1024, 256, 0, stream>>>(nf, We, Wn, nfb, Web, Wnb, bhist, cnts);
    k_binhist<<<256, 256, 0, stream>>>(edst, ntp, bhist, cnts);
    k_binscan<<<1, 512, 0, stream>>>(bhist, binptr, bincur, rowptr);
    k_mid<<<NEB + NCH2 + NT * TILES2, 512, 0, stream>>>(nfb, Web, be, M,
            esrc, edst, et, ntp, bincur, cnts, pe, sn, rnk);
    k_binsort<<<NBINS, 512, 0, stream>>>(binptr, pe, rowptr);
    k_agg<<<NN / 8, 128, 0, stream>>>(M, rowptr, pe, rnk, aggb);
    k_node<<<NTILE_PAD, 256, 0, stream>>>(nf, nfb, Wnb, bn, sn, cnts, aggb, out);
}